// Round 13
// baseline (185.364 us; speedup 1.0000x reference)
//
#include <hip/hip_runtime.h>
#include <hip/hip_bf16.h>
#include <hip/hip_cooperative_groups.h>

namespace cg = cooperative_groups;

typedef __hip_bfloat16 bf16;
typedef __attribute__((ext_vector_type(8))) short short8;
typedef __attribute__((ext_vector_type(4))) float f32x4;

#define NPTS 4096
#define CCH  128

static __device__ __forceinline__ short f2b(float x) {
    bf16 h = __float2bfloat16(x);
    return __builtin_bit_cast(short, h);
}
static __device__ __forceinline__ float b2f(short x) {
    return __bfloat162float(__builtin_bit_cast(bf16, x));
}

struct WPtrs { const void* src[16]; int start[17]; };

struct MArgs {
    const void* eigen;
    WPtrs P;
    int total;
    short *eb, *qfb, *kfb, *vfb, *avb, *h1ab, *h1, *wpb, *wmhT;
    float *wfa, *bprime, *part;
    int *flagp;
    const short *wbq, *wbk, *wbv, *wbc1, *wbc2;
    const float *bqf, *bkf, *bvf, *bmhf, *wc1f, *bc1f, *gf, *bef, *bc2f, *wtf, *btf;
    void* out;
};

// ---------------- MFMA acc core: acc[f] += A[n][:]·W[o0+16f+lo][:] ----------------
template<int OFRAG, int BNA>
static __device__ __forceinline__ void gemm_accs(
    int n0, int o0, int lo, int hi,
    const short* __restrict__ A, int alda,
    const short* __restrict__ W, int wlda, int K,
    const float* scL, const float* shL, f32x4* acc)
{
    const short* Ar = A + (n0 + lo) * alda + 8 * hi;
#pragma unroll 4
    for (int kk = 0; kk < K; kk += 32) {
        short8 aF = *(const short8*)(Ar + kk);
        if (BNA) {
#pragma unroll
            for (int j = 0; j < 8; ++j) {
                int c = kk + 8 * hi + j;
                aF[j] = f2b(fmaxf(scL[c] * b2f(aF[j]) + shL[c], 0.f));
            }
        }
#pragma unroll
        for (int f = 0; f < OFRAG; ++f) {
            short8 bF = *(const short8*)(W + (o0 + 16 * f + lo) * wlda + 8 * hi + kk);
            acc[f] = __builtin_amdgcn_mfma_f32_16x16x32_bf16(aF, bF, acc[f], 0, 0, 0);
        }
    }
}

// ---------------- swapped GEMM (V): fragment-linear output ----------------
static __device__ __forceinline__ void gemm_tn_body(
    int bx, int by, int t2,
    const short* __restrict__ W, const short* __restrict__ A,
    const float* __restrict__ bias, short* __restrict__ out)
{
    const int w = t2 >> 6, lane = t2 & 63;
    const int lo = lane & 15, hi = lane >> 4;
    const int o0 = by * 16;
    const int n0 = bx * 128 + w * 32;
    const f32x4 z = {0.f, 0.f, 0.f, 0.f};
    f32x4 acc0 = z, acc1 = z;
    const short* Wr = W + (o0 + lo) * CCH + 8 * hi;
    const short* A0 = A + (n0 + lo) * CCH + 8 * hi;
    const short* A1 = A + (n0 + 16 + lo) * CCH + 8 * hi;
#pragma unroll
    for (int kk = 0; kk < 128; kk += 32) {
        short8 aW = *(const short8*)(Wr + kk);
        short8 b0 = *(const short8*)(A0 + kk);
        short8 b1 = *(const short8*)(A1 + kk);
        acc0 = __builtin_amdgcn_mfma_f32_16x16x32_bf16(aW, b0, acc0, 0, 0, 0);
        acc1 = __builtin_amdgcn_mfma_f32_16x16x32_bf16(aW, b1, acc1, 0, 0, 0);
    }
    const int s1 = 8 * (lo >> 2) + (lo & 3);
    const int s2 = s1 + 4;
    const int m32 = n0 >> 5;
#pragma unroll
    for (int r = 0; r < 4; ++r) {
        int o = o0 + 4 * hi + r;
        float bb = bias[o];
        int hd = o >> 5, c32 = o & 31, dt = c32 >> 4, lov = c32 & 15;
        int base = ((hd * 128 + m32) * 2 + dt) * 512 + lov * 8;
        out[base + (s1 >> 3) * 128 + (s1 & 7)] = f2b(acc0[r] + bb);
        out[base + (s2 >> 3) * 128 + (s2 & 7)] = f2b(acc1[r] + bb);
    }
}

// ======================= single cooperative mega-kernel =======================
// grid = 256 blocks x 1024 thr (1 block/CU). 5 phases, 4 grid syncs.
__global__ __launch_bounds__(1024, 4) void mega_kernel(MArgs A)
{
    cg::grid_group grid = cg::this_grid();
    const int tid = threadIdx.x, bid = blockIdx.x;
    const int u = tid >> 8, t2 = tid & 255;

    __shared__ __align__(16) char smem[73728];
    __shared__ int sflag;

    // ---------------- P0: detect + eigen transpose + weight convert ----------------
    {
        int cnt = 0;
        if (tid < 64) {
            const unsigned short* uu = (const unsigned short*)A.eigen;
#pragma unroll
            for (int i = 0; i < 16; ++i) {
                int e = (uu[tid * 16 + i] >> 7) & 0xFF;
                cnt += (e >= 0x8F);
            }
#pragma unroll
            for (int off = 32; off > 0; off >>= 1) cnt += __shfl_down(cnt, off);
            if (tid == 0) sflag = (cnt >= 16);
        }
        __syncthreads();
    }
    const int fl = sflag;

    if (bid < 32) {
        // 4 transpose tiles per block (sub-unit u), block-uniform __syncthreads
        float (*tile)[64][65] = (float (*)[64][65])smem;
        const int tb = bid * 4 + u;              // 0..127
        const int n0 = (tb & 63) * 64, c0 = (tb >> 6) * 64;
        const int tx = t2 & 63, ty = t2 >> 6;
#pragma unroll
        for (int it = 0; it < 16; ++it) {
            int cl = 4 * it + ty;
            float v = fl ? ((const float*)A.eigen)[(c0 + cl) * NPTS + n0 + tx]
                         : b2f(((const short*)A.eigen)[(c0 + cl) * NPTS + n0 + tx]);
            tile[u][tx][cl] = v;
        }
        __syncthreads();
#pragma unroll
        for (int ot = 0; ot < 16; ++ot) {
            int nl = 4 * ot + ty;
            A.eb[(n0 + nl) * CCH + c0 + tx] = f2b(tile[u][nl][tx]);
        }
    } else {
        if (bid == 32) {
            if (tid == 0) *A.flagp = fl;
            if (tid < 512) A.part[tid] = 0.f;
        }
        int i = (bid - 32) * 1024 + tid;
        if (i < A.total) {
            int s = 0;
#pragma unroll 1
            for (int k2 = 0; k2 < 16; ++k2) if (i >= A.P.start[k2 + 1]) s = k2 + 1;
            int off = i - A.P.start[s];
            float v = fl ? ((const float*)A.P.src[s])[off]
                         : b2f(((const short*)A.P.src[s])[off]);
            if (s < 2) v *= 0.25503506f;   // fold 1/sqrt(hd)*log2(e) into wq,bq
            A.wfa[i] = v;
            short vb = f2b(v);
            ((short*)A.wfa)[0];  // no-op
            ((short*)(A.wfa))[0];
            // bf16 arena lives right after f32 arena (same indexing)
            ((short*)(A.wfa + A.P.start[16]))[i] = vb;
            if (s == 6) A.wmhT[(off & 127) * 128 + (off >> 7)] = vb;  // wmh^T
        }
    }
    grid.sync();

    // ---------------- P1: QK | h1a | V | W' | b'  (777 sub-units of 256) ----------------
    {
        const int sub = u * 256 + bid;           // even spread across blocks
        const int w = t2 >> 6, lane = t2 & 63;
        const int lo = lane & 15, hi = lane >> 4;
        const f32x4 z = {0.f, 0.f, 0.f, 0.f};
        if (sub < 256) {            // Q (sub<128) or K -> fragment-linear
            const int isK = sub >> 7, bx = sub & 127;
            const int n0 = bx * 32 + (w & 1) * 16, o0 = (w >> 1) * 64;
            f32x4 acc[4] = {z, z, z, z};
            gemm_accs<4, 0>(n0, o0, lo, hi, A.eb, CCH, isK ? A.wbk : A.wbq, CCH, 128,
                            nullptr, nullptr, acc);
            const float* bp = isK ? A.bkf : A.bqf;
            short* dst = isK ? A.kfb : A.qfb;
            const int tile16 = n0 >> 4;
#pragma unroll
            for (int f = 0; f < 4; ++f) {
                int col = o0 + 16 * f + lo;
                int hd = col >> 5, c32 = col & 31;
                int base = hd * 131072 + tile16 * 512 + (c32 >> 3) * 128 + (c32 & 7);
#pragma unroll
                for (int r = 0; r < 4; ++r)
                    dst[base + (4 * hi + r) * 8] = f2b(acc[f][r] + bp[col]);
            }
        } else if (sub < 512) {     // h1a = wc1a @ eigen, bf16 [4096][256]
            const int b3 = sub - 256, bx = b3 & 127, by = b3 >> 7;
            const int n0 = bx * 32 + (w & 1) * 16, o0 = by * 128 + (w >> 1) * 64;
            f32x4 acc[4] = {z, z, z, z};
            gemm_accs<4, 0>(n0, o0, lo, hi, A.eb, CCH, A.wbc1, 256, 128,
                            nullptr, nullptr, acc);
#pragma unroll
            for (int f = 0; f < 4; ++f) {
                int col = o0 + 16 * f + lo;
#pragma unroll
                for (int r = 0; r < 4; ++r)
                    A.h1ab[(n0 + 4 * hi + r) * 256 + col] = f2b(acc[f][r]);
            }
        } else if (sub < 768) {     // V -> fragment-linear
            int b2 = sub - 512;
            gemm_tn_body(b2 & 31, b2 >> 5, t2, A.wbv, A.eb, A.bvf, A.vfb);
        } else if (sub < 776) {     // W' = wc1b @ wmh
            const int bx = sub - 768;
            const int n0 = bx * 32 + (w & 1) * 16, o0 = (w >> 1) * 64;
            f32x4 acc[4] = {z, z, z, z};
            gemm_accs<4, 0>(n0, o0, lo, hi, A.wbc1 + 128, 256, A.wmhT, 128, 128,
                            nullptr, nullptr, acc);
#pragma unroll
            for (int f = 0; f < 4; ++f) {
                int col = o0 + 16 * f + lo;
#pragma unroll
                for (int r = 0; r < 4; ++r)
                    A.wpb[(n0 + 4 * hi + r) * 128 + col] = f2b(acc[f][r]);
            }
        } else if (sub == 776) {    // b' = bc1 + wc1b @ bmh
            float a = A.bc1f[t2];
            const float* row = A.wc1f + t2 * 256 + 128;
#pragma unroll 8
            for (int k = 0; k < 128; ++k) a = fmaf(row[k], A.bmhf[k], a);
            A.bprime[t2] = a;
        }
    }
    grid.sync();

    // ---------------- P2: attention (identical to round-12 kernel) ----------------
    {
        const int wid = tid >> 6, lane = tid & 63;
        const int lo = lane & 15, hi = lane >> 4;
        const int h = bid >> 6;
        const int qblk = bid & 63;
        const int q0 = qblk * 64;
        const int hc = h * 32;
        const int lofs = hi * 128 + lo * 8;

        float (*accb)[64][17] = (float (*)[64][17])smem;          // 69632 B
        float (*lbuf)[4][16]  = (float (*)[4][16])(smem + 69632); // 4096 B

        const short* qh = A.qfb + h * 131072;
        const short* kh = A.kfb + h * 131072;
        const short* vh = A.vfb + h * 131072;

        short8 qf[4];
#pragma unroll
        for (int f = 0; f < 4; ++f)
            qf[f] = *(const short8*)(qh + ((q0 >> 4) + f) * 512 + lofs);

        const f32x4 z = {0.f, 0.f, 0.f, 0.f};
        f32x4 o[4][2] = {{z, z}, {z, z}, {z, z}, {z, z}};
        float l[4] = {0.f, 0.f, 0.f, 0.f};

        for (int t = 0; t < 4; ++t) {
            const int m0 = wid * 256 + t * 64;
            short8 kf[4], vf[4];
#pragma unroll
            for (int mt = 0; mt < 4; ++mt)
                kf[mt] = *(const short8*)(kh + ((m0 >> 4) + mt) * 512 + lofs);
#pragma unroll
            for (int kt = 0; kt < 2; ++kt)
#pragma unroll
                for (int dt = 0; dt < 2; ++dt)
                    vf[kt * 2 + dt] = *(const short8*)(vh + (((m0 >> 5) + kt) * 2 + dt) * 512 + lofs);

#pragma unroll
            for (int f = 0; f < 4; ++f) {
                f32x4 s[4];
#pragma unroll
                for (int mt = 0; mt < 4; ++mt)
                    s[mt] = __builtin_amdgcn_mfma_f32_16x16x32_bf16(kf[mt], qf[f], z, 0, 0, 0);

                float p[4][4];
                float sm = 0.f;
#pragma unroll
                for (int mt = 0; mt < 4; ++mt)
#pragma unroll
                    for (int r = 0; r < 4; ++r) {
                        float pv = __builtin_amdgcn_exp2f(s[mt][r]);
                        p[mt][r] = pv;
                        sm += pv;
                    }
                sm += __shfl_xor(sm, 16);
                sm += __shfl_xor(sm, 32);
                l[f] += sm;

                short8 pa1, pa2;
#pragma unroll
                for (int j = 0; j < 8; ++j) {
                    pa1[j] = f2b(p[j >> 2][j & 3]);
                    pa2[j] = f2b(p[2 + (j >> 2)][j & 3]);
                }
                o[f][0] = __builtin_amdgcn_mfma_f32_16x16x32_bf16(pa1, vf[0], o[f][0], 0, 0, 0);
                o[f][1] = __builtin_amdgcn_mfma_f32_16x16x32_bf16(pa1, vf[1], o[f][1], 0, 0, 0);
                o[f][0] = __builtin_amdgcn_mfma_f32_16x16x32_bf16(pa2, vf[2], o[f][0], 0, 0, 0);
                o[f][1] = __builtin_amdgcn_mfma_f32_16x16x32_bf16(pa2, vf[3], o[f][1], 0, 0, 0);
            }
        }

        if (hi == 0) {
#pragma unroll
            for (int f = 0; f < 4; ++f) lbuf[wid][f][lo] = l[f];
        }
        {
            float* mine = &accb[wid][lane][0];
#pragma unroll
            for (int f = 0; f < 4; ++f)
#pragma unroll
                for (int r = 0; r < 4; ++r) mine[f * 4 + r] = o[f][0][r];
        }
        __syncthreads();

        const int e = tid >> 6;
        const int lane_s = tid & 63;
        const int lo_s = lane_s & 15, hi_s = lane_s >> 4;
        const int fm = e >> 2, r = e & 3;
        const int ql = 16 * fm + 4 * hi_s + r;
        float lm = 0.f;
        {
            float sum = 0.f;
#pragma unroll
            for (int s = 0; s < 16; ++s) {
                sum += accb[s][lane_s][e];
                lm  += lbuf[s][fm][4 * hi_s + r];
            }
            A.avb[(q0 + ql) * CCH + hc + lo_s] = f2b(sum / lm);
        }
        __syncthreads();
        {
            float* mine = &accb[wid][lane][0];
#pragma unroll
            for (int f = 0; f < 4; ++f)
#pragma unroll
                for (int r2 = 0; r2 < 4; ++r2) mine[f * 4 + r2] = o[f][1][r2];
        }
        __syncthreads();
        {
            float sum = 0.f;
#pragma unroll
            for (int s = 0; s < 16; ++s) sum += accb[s][lane_s][e];
            A.avb[(q0 + ql) * CCH + hc + 16 + lo_s] = f2b(sum / lm);
        }
    }
    grid.sync();

    // ---------------- P3: c1b (512 sub-units of 256, waves 0..7 per block) ----------------
    if (u < 2) {
        const int sub = u * 256 + bid;            // 0..511
        const int bx = sub & 127, by = sub >> 7;
        const int w = t2 >> 6, lane = t2 & 63;
        const int lo = lane & 15, hi = lane >> 4;
        const int n0 = bx * 32 + (w & 1) * 16;
        const int o0 = by * 64 + (w >> 1) * 32;
        const f32x4 z = {0.f, 0.f, 0.f, 0.f};
        f32x4 acc[2] = {z, z};
        gemm_accs<2, 0>(n0, o0, lo, hi, A.avb, CCH, A.wpb, CCH, 128, nullptr, nullptr, acc);

        const int oa = o0 + lo, ob = o0 + 16 + lo;
        float s0 = 0.f, q0 = 0.f, s1 = 0.f, q1 = 0.f;
#pragma unroll
        for (int r = 0; r < 4; ++r) {
            int n = n0 + 4 * hi + r;
            float v0 = acc[0][r] + A.bprime[oa] + b2f(A.h1ab[n * 256 + oa]);
            float v1 = acc[1][r] + A.bprime[ob] + b2f(A.h1ab[n * 256 + ob]);
            A.h1[n * 256 + oa] = f2b(v0);
            A.h1[n * 256 + ob] = f2b(v1);
            s0 += v0; q0 += v0 * v0; s1 += v1; q1 += v1 * v1;
        }
        s0 += __shfl_xor(s0, 16); s0 += __shfl_xor(s0, 32);
        q0 += __shfl_xor(q0, 16); q0 += __shfl_xor(q0, 32);
        s1 += __shfl_xor(s1, 16); s1 += __shfl_xor(s1, 32);
        q1 += __shfl_xor(q1, 16); q1 += __shfl_xor(q1, 32);
        if (hi == 0) {
            atomicAdd(&A.part[oa], s0);  atomicAdd(&A.part[256 + oa], q0);
            atomicAdd(&A.part[ob], s1);  atomicAdd(&A.part[256 + ob], q1);
        }
    }
    grid.sync();

    // ---------------- P4: c2f (256 blocks x 16 rows, 4 active waves) ----------------
    {
        float* scL = (float*)smem;              // 256 f
        float* shL = scL + 256;                 // 256 f
        float* wts = shL + 256;                 // 384 f
        float (*red)[16][3] = (float (*)[16][3])(wts + 384);  // [4][16][3]

        if (tid < 256) {
            float mean = A.part[tid] * (1.f / NPTS);
            float var  = A.part[256 + tid] * (1.f / NPTS) - mean * mean;
            float iv   = rsqrtf(var + 1e-5f);
            float sc   = A.gf[tid] * iv;
            scL[tid] = sc;
            shL[tid] = A.bef[tid] - mean * sc;
        }
        for (int i = tid; i < 384; i += 1024) wts[i] = A.wtf[i];
        __syncthreads();

        if (tid < 256) {
            const int w = t2 >> 6, lane = t2 & 63;
            const int lo = lane & 15, hi = lane >> 4;
            const int n0 = bid * 16;
            const int o0 = w * 32;
            const f32x4 z = {0.f, 0.f, 0.f, 0.f};
            f32x4 acc[2] = {z, z};
            gemm_accs<2, 1>(n0, o0, lo, hi, A.h1, 256, A.wbc2, 256, 256, scL, shL, acc);

            float pr[4][3] = {};
#pragma unroll
            for (int f = 0; f < 2; ++f) {
                int col = o0 + 16 * f + lo;
                float w0 = wts[col], w1 = wts[128 + col], w2 = wts[256 + col];
                float bb = A.bc2f[col];
#pragma unroll
                for (int r = 0; r < 4; ++r) {
                    int n = n0 + 4 * hi + r;
                    float v = acc[f][r] + bb + b2f(A.eb[n * CCH + col]);
                    pr[r][0] += v * w0; pr[r][1] += v * w1; pr[r][2] += v * w2;
                }
            }
#pragma unroll
            for (int r = 0; r < 4; ++r)
#pragma unroll
                for (int d = 0; d < 3; ++d) {
                    float x = pr[r][d];
                    x += __shfl_xor(x, 1); x += __shfl_xor(x, 2);
                    x += __shfl_xor(x, 4); x += __shfl_xor(x, 8);
                    pr[r][d] = x;
                }
            if (lo == 0) {
#pragma unroll
                for (int r = 0; r < 4; ++r)
#pragma unroll
                    for (int d = 0; d < 3; ++d)
                        red[w][4 * hi + r][d] = pr[r][d];
            }
        }
        __syncthreads();
        if (tid < 48) {
            int nl = tid / 3, d = tid - nl * 3;
            float v = red[0][nl][d] + red[1][nl][d] + red[2][nl][d] + red[3][nl][d]
                      + A.btf[d];
            int gn = bid * 16 + nl;
            if (*A.flagp) ((float*)A.out)[gn * 3 + d] = v;
            else          ((bf16*)A.out)[gn * 3 + d] = __float2bfloat16(v);
        }
    }
}

extern "C" void kernel_launch(void* const* d_in, const int* in_sizes, int n_in,
                              void* d_out, int out_size, void* d_ws, size_t ws_size,
                              hipStream_t stream) {
    const int CN = CCH * NPTS;  // 524288
    float* ws = (float*)d_ws;
    size_t fo = 0;
    auto FA = [&](size_t n) { float* p = ws + fo; fo += n; return p; };
    short* eb     = (short*)FA(CN / 2);
    short* qfb    = (short*)FA(CN / 2);
    short* kfb    = (short*)FA(CN / 2);
    short* vfb    = (short*)FA(CN / 2);
    short* avb    = (short*)FA(CN / 2);
    short* h1ab   = (short*)FA(CN);
    short* h1     = (short*)FA(CN);
    short* wpb    = (short*)FA(16384);
    short* wmhT   = (short*)FA(8192);
    float* bprime = FA(256);
    float* part   = FA(512);
    int*   flagp  = (int*)FA(16);
    float* wfa    = ws + fo;

    MArgs a;
    a.eigen = d_in[0];
    int acc = 0;
    int st[17];
    for (int i = 1; i < 17; ++i) {
        a.P.src[i - 1] = d_in[i];
        a.P.start[i - 1] = acc;
        st[i] = acc;
        acc += (in_sizes[i] + 3) & ~3;
    }
    a.P.start[16] = acc;
    a.total = acc;
    short* wba = (short*)(wfa + acc);   // bf16 arena right after f32 arena

    a.eb = eb; a.qfb = qfb; a.kfb = kfb; a.vfb = vfb; a.avb = avb;
    a.h1ab = h1ab; a.h1 = h1; a.wpb = wpb; a.wmhT = wmhT;
    a.wfa = wfa; a.bprime = bprime; a.part = part; a.flagp = flagp;
    a.wbq  = wba + st[1];
    a.wbk  = wba + st[3];
    a.wbv  = wba + st[5];
    a.wbc1 = wba + st[9];
    a.wbc2 = wba + st[13];
    a.bqf  = wfa + st[2];
    a.bkf  = wfa + st[4];
    a.bvf  = wfa + st[6];
    a.bmhf = wfa + st[8];
    a.wc1f = wfa + st[9];
    a.bc1f = wfa + st[10];
    a.gf   = wfa + st[11];
    a.bef  = wfa + st[12];
    a.bc2f = wfa + st[14];
    a.wtf  = wfa + st[15];
    a.btf  = wfa + st[16];
    a.out  = d_out;

    void* kargs[] = { &a };
    hipLaunchCooperativeKernel((void*)mega_kernel, dim3(256), dim3(1024),
                               kargs, 0, stream);
}

// Round 14
// 69.087 us; speedup vs baseline: 2.6830x; 2.6830x over previous
//
#include <hip/hip_runtime.h>
#include <hip/hip_bf16.h>

typedef __hip_bfloat16 bf16;
typedef __attribute__((ext_vector_type(8))) short short8;
typedef __attribute__((ext_vector_type(4))) float f32x4;

#define NPTS 4096
#define CCH  128

static __device__ __forceinline__ short f2b(float x) {
    bf16 h = __float2bfloat16(x);
    return __builtin_bit_cast(short, h);
}
static __device__ __forceinline__ float b2f(short x) {
    return __bfloat162float(__builtin_bit_cast(bf16, x));
}

struct WPtrs { const void* src[16]; int start[17]; };

// ---------------- prep: detect + eigen transpose(bf16) + weight convert ----------------
__global__ __launch_bounds__(256) void prep_kernel(
    const void* __restrict__ eigen, WPtrs P,
    short* __restrict__ eb,
    float* __restrict__ wfa, short* __restrict__ wba, short* __restrict__ wmhT,
    float* __restrict__ part, int* __restrict__ flagp, int total)
{
    const int tid = threadIdx.x, bid = blockIdx.x;
    __shared__ int sflag;
    {
        int cnt = 0;
        if (tid < 64) {
            const unsigned short* u = (const unsigned short*)eigen;
#pragma unroll
            for (int i = 0; i < 16; ++i) {
                int e = (u[tid * 16 + i] >> 7) & 0xFF;
                cnt += (e >= 0x8F);
            }
#pragma unroll
            for (int off = 32; off > 0; off >>= 1) cnt += __shfl_down(cnt, off);
            if (tid == 0) sflag = (cnt >= 16);
        }
        __syncthreads();
    }
    const int f = sflag;

    if (bid < 128) {
        __shared__ float tile[64][65];
        const int tx = tid & 63, ty = tid >> 6;
        const int n0 = (bid & 63) * 64, c0 = (bid >> 6) * 64;
#pragma unroll
        for (int it = 0; it < 16; ++it) {
            int cl = 4 * it + ty;
            float v = f ? ((const float*)eigen)[(c0 + cl) * NPTS + n0 + tx]
                        : b2f(((const short*)eigen)[(c0 + cl) * NPTS + n0 + tx]);
            tile[tx][cl] = v;
        }
        __syncthreads();
#pragma unroll
        for (int ot = 0; ot < 16; ++ot) {
            int nl = 4 * ot + ty;
            eb[(n0 + nl) * CCH + c0 + tx] = f2b(tile[nl][tx]);
        }
    } else {
        if (bid == 128) {
            if (tid == 0) *flagp = f;
            part[tid] = 0.f; part[256 + tid] = 0.f;
        }
        int i = (bid - 128) * 256 + tid;
        if (i < total) {
            int s = 0;
#pragma unroll 1
            for (int k2 = 0; k2 < 16; ++k2) if (i >= P.start[k2 + 1]) s = k2 + 1;
            int off = i - P.start[s];
            float v = f ? ((const float*)P.src[s])[off]
                        : b2f(((const short*)P.src[s])[off]);
            // fold 1/sqrt(hd) * log2(e) into wq,bq -> softmax uses exp2 directly
            if (s < 2) v *= 0.25503506f;
            wfa[i] = v;
            short vb = f2b(v);
            wba[i] = vb;
            if (s == 6) wmhT[(off & 127) * 128 + (off >> 7)] = vb;  // wmh^T
        }
    }
}

// ---------------- MFMA acc core: acc[f] += A[n][:]·W[o0+16f+lo][:] ----------------
template<int OFRAG, int BNA>
static __device__ __forceinline__ void gemm_accs(
    int n0, int o0, int lo, int hi,
    const short* __restrict__ A, int alda,
    const short* __restrict__ W, int wlda, int K,
    const float* scL, const float* shL, f32x4* acc)
{
    const short* Ar = A + (n0 + lo) * alda + 8 * hi;
#pragma unroll 4
    for (int kk = 0; kk < K; kk += 32) {
        short8 aF = *(const short8*)(Ar + kk);
        if (BNA) {
#pragma unroll
            for (int j = 0; j < 8; ++j) {
                int c = kk + 8 * hi + j;
                aF[j] = f2b(fmaxf(scL[c] * b2f(aF[j]) + shL[c], 0.f));
            }
        }
#pragma unroll
        for (int f = 0; f < OFRAG; ++f) {
            short8 bF = *(const short8*)(W + (o0 + 16 * f + lo) * wlda + 8 * hi + kk);
            acc[f] = __builtin_amdgcn_mfma_f32_16x16x32_bf16(aF, bF, acc[f], 0, 0, 0);
        }
    }
}

// ---------------- swapped GEMM (V): fragment-linear output ----------------
// Vf layout: addr(head, m, c32) = ((head*128 + (m>>5))*2 + (c32>>4))*512
//            + (s>>3)*128 + (c32&15)*8 + (s&7),  s = 8*((m>>2)&3)+(m&3)+4*((m>>4)&1)
static __device__ __forceinline__ void gemm_tn_body(
    int bx, int by, int tid,
    const short* __restrict__ W, const short* __restrict__ A,
    const float* __restrict__ bias, short* __restrict__ out)
{
    const int w = tid >> 6, lane = tid & 63;
    const int lo = lane & 15, hi = lane >> 4;
    const int o0 = by * 16;
    const int n0 = bx * 128 + w * 32;
    const f32x4 z = {0.f, 0.f, 0.f, 0.f};
    f32x4 acc0 = z, acc1 = z;
    const short* Wr = W + (o0 + lo) * CCH + 8 * hi;
    const short* A0 = A + (n0 + lo) * CCH + 8 * hi;
    const short* A1 = A + (n0 + 16 + lo) * CCH + 8 * hi;
#pragma unroll
    for (int kk = 0; kk < 128; kk += 32) {
        short8 aW = *(const short8*)(Wr + kk);
        short8 b0 = *(const short8*)(A0 + kk);
        short8 b1 = *(const short8*)(A1 + kk);
        acc0 = __builtin_amdgcn_mfma_f32_16x16x32_bf16(aW, b0, acc0, 0, 0, 0);
        acc1 = __builtin_amdgcn_mfma_f32_16x16x32_bf16(aW, b1, acc1, 0, 0, 0);
    }
    const int s1 = 8 * (lo >> 2) + (lo & 3);
    const int s2 = s1 + 4;
    const int m32 = n0 >> 5;
#pragma unroll
    for (int r = 0; r < 4; ++r) {
        int o = o0 + 4 * hi + r;
        float bb = bias[o];
        int hd = o >> 5, c32 = o & 31, dt = c32 >> 4, lov = c32 & 15;
        int base = ((hd * 128 + m32) * 2 + dt) * 512 + lov * 8;
        out[base + (s1 >> 3) * 128 + (s1 & 7)] = f2b(acc0[r] + bb);
        out[base + (s2 >> 3) * 128 + (s2 & 7)] = f2b(acc1[r] + bb);
    }
}

// ---------------- pre-attention fused launch: QK | h1a | V | W' | b' ----------------
__global__ __launch_bounds__(256) void qkv_kernel(
    const short* __restrict__ eb,
    const short* __restrict__ wbq, const short* __restrict__ wbk,
    const short* __restrict__ wbv, const short* __restrict__ wbc1,
    const short* __restrict__ wmhT,
    const float* __restrict__ bqf, const float* __restrict__ bkf,
    const float* __restrict__ bvf, const float* __restrict__ bc1f,
    const float* __restrict__ bmhf, const float* __restrict__ wc1f,
    short* __restrict__ qfb, short* __restrict__ kfb, short* __restrict__ vfb,
    short* __restrict__ h1ab, short* __restrict__ wpb, float* __restrict__ bprime)
{
    const int bid = blockIdx.x, tid = threadIdx.x;
    const int w = tid >> 6, lane = tid & 63;
    const int lo = lane & 15, hi = lane >> 4;
    const f32x4 z = {0.f, 0.f, 0.f, 0.f};

    if (bid < 256) {            // Q (bid<128) or K -> fragment-linear buffers
        const int isK = bid >> 7, bx = bid & 127;
        const int n0 = bx * 32 + (w & 1) * 16, o0 = (w >> 1) * 64;
        f32x4 acc[4] = {z, z, z, z};
        gemm_accs<4, 0>(n0, o0, lo, hi, eb, CCH, isK ? wbk : wbq, CCH, 128,
                        nullptr, nullptr, acc);
        const float* bp = isK ? bkf : bqf;
        short* dst = isK ? kfb : qfb;
        const int tile = n0 >> 4;
#pragma unroll
        for (int f = 0; f < 4; ++f) {
            int col = o0 + 16 * f + lo;
            int hd = col >> 5, c32 = col & 31;
            int base = hd * 131072 + tile * 512 + (c32 >> 3) * 128 + (c32 & 7);
#pragma unroll
            for (int r = 0; r < 4; ++r)
                dst[base + (4 * hi + r) * 8] = f2b(acc[f][r] + bp[col]);
        }
    } else if (bid < 512) {     // h1a = wc1a @ eigen, bf16 [4096][256]
        const int b3 = bid - 256, bx = b3 & 127, by = b3 >> 7;
        const int n0 = bx * 32 + (w & 1) * 16, o0 = by * 128 + (w >> 1) * 64;
        f32x4 acc[4] = {z, z, z, z};
        gemm_accs<4, 0>(n0, o0, lo, hi, eb, CCH, wbc1, 256, 128, nullptr, nullptr, acc);
#pragma unroll
        for (int f = 0; f < 4; ++f) {
            int col = o0 + 16 * f + lo;
#pragma unroll
            for (int r = 0; r < 4; ++r)
                h1ab[(n0 + 4 * hi + r) * 256 + col] = f2b(acc[f][r]);
        }
    } else if (bid < 768) {     // V -> fragment-linear vfb
        int b2 = bid - 512;
        gemm_tn_body(b2 & 31, b2 >> 5, tid, wbv, eb, bvf, vfb);
    } else if (bid < 776) {     // W' = wc1b @ wmh, bf16 [256][128]
        const int bx = bid - 768;
        const int n0 = bx * 32 + (w & 1) * 16, o0 = (w >> 1) * 64;
        f32x4 acc[4] = {z, z, z, z};
        gemm_accs<4, 0>(n0, o0, lo, hi, wbc1 + 128, 256, wmhT, 128, 128,
                        nullptr, nullptr, acc);
#pragma unroll
        for (int f = 0; f < 4; ++f) {
            int col = o0 + 16 * f + lo;
#pragma unroll
            for (int r = 0; r < 4; ++r)
                wpb[(n0 + 4 * hi + r) * 128 + col] = f2b(acc[f][r]);
        }
    } else {                    // b' = bc1 + wc1b @ bmh
        float a = bc1f[tid];
        const float* row = wc1f + tid * 256 + 128;
#pragma unroll 8
        for (int k = 0; k < 128; ++k) a = fmaf(row[k], bmhf[k], a);
        bprime[tid] = a;
    }
}

// ---------------- MFMA flash attention: fragment-linear, 64q/wave, dbuf prefetch ----------------
// grid = H*64 blocks x 1024 thr (16 waves = 16-way KV split, each wave does 64 q).
// Register double-buffer: t+1's K/V loads issue before t's compute.
__global__ __launch_bounds__(1024, 4) void attn_kernel(
    const short* __restrict__ qF, const short* __restrict__ kF,
    const short* __restrict__ vF, short* __restrict__ av) {
    const int tid = threadIdx.x;
    const int wid = tid >> 6, lane = tid & 63;
    const int lo = lane & 15, hi = lane >> 4;
    const int h = blockIdx.x >> 6;
    const int qblk = blockIdx.x & 63;
    const int q0 = qblk * 64;
    const int hc = h * 32;
    const int lofs = hi * 128 + lo * 8;

    __shared__ __align__(16) float accb[16][64][17];  // 69.6 KB, pad-17 bank-free
    __shared__ float lbuf[16][4][16];                  // 4 KB row-sum partials

    const short* qh = qF + h * 131072;
    const short* kh = kF + h * 131072;
    const short* vh = vF + h * 131072;

    short8 qf[4];
#pragma unroll
    for (int f = 0; f < 4; ++f)
        qf[f] = *(const short8*)(qh + ((q0 >> 4) + f) * 512 + lofs);

    const f32x4 z = {0.f, 0.f, 0.f, 0.f};
    f32x4 o[4][2] = {{z, z}, {z, z}, {z, z}, {z, z}};  // o[f][dt]
    float l[4] = {0.f, 0.f, 0.f, 0.f};

    short8 kf[2][4], vf[2][4];
    auto loadKV = [&](int t, int b) {
        const int m0 = wid * 256 + t * 64;
#pragma unroll
        for (int mt = 0; mt < 4; ++mt)
            kf[b][mt] = *(const short8*)(kh + ((m0 >> 4) + mt) * 512 + lofs);
#pragma unroll
        for (int kt = 0; kt < 2; ++kt)
#pragma unroll
            for (int dt = 0; dt < 2; ++dt)
                vf[b][kt * 2 + dt] = *(const short8*)(vh + (((m0 >> 5) + kt) * 2 + dt) * 512 + lofs);
    };

    loadKV(0, 0);
#pragma unroll
    for (int t = 0; t < 4; ++t) {
        const int cur = t & 1;
        if (t < 3) loadKV(t + 1, cur ^ 1);   // prefetch overlaps compute below

#pragma unroll
        for (int f = 0; f < 4; ++f) {
            f32x4 s[4];
#pragma unroll
            for (int mt = 0; mt < 4; ++mt)
                s[mt] = __builtin_amdgcn_mfma_f32_16x16x32_bf16(kf[cur][mt], qf[f], z, 0, 0, 0);

            float p[4][4];
            float sm = 0.f;
#pragma unroll
            for (int mt = 0; mt < 4; ++mt)
#pragma unroll
                for (int r = 0; r < 4; ++r) {
                    float pv = __builtin_amdgcn_exp2f(s[mt][r]);
                    p[mt][r] = pv;
                    sm += pv;
                }
            sm += __shfl_xor(sm, 16);
            sm += __shfl_xor(sm, 32);
            l[f] += sm;

            short8 pa1, pa2;
#pragma unroll
            for (int j = 0; j < 8; ++j) {
                pa1[j] = f2b(p[j >> 2][j & 3]);
                pa2[j] = f2b(p[2 + (j >> 2)][j & 3]);
            }
            o[f][0] = __builtin_amdgcn_mfma_f32_16x16x32_bf16(pa1, vf[cur][0], o[f][0], 0, 0, 0);
            o[f][1] = __builtin_amdgcn_mfma_f32_16x16x32_bf16(pa1, vf[cur][1], o[f][1], 0, 0, 0);
            o[f][0] = __builtin_amdgcn_mfma_f32_16x16x32_bf16(pa2, vf[cur][2], o[f][0], 0, 0, 0);
            o[f][1] = __builtin_amdgcn_mfma_f32_16x16x32_bf16(pa2, vf[cur][3], o[f][1], 0, 0, 0);
        }
    }

    // ---- merge 16 KV partials, two d-half phases, all-wave parallel ----
    if (hi == 0) {
#pragma unroll
        for (int f = 0; f < 4; ++f) lbuf[wid][f][lo] = l[f];
    }
    {
        float* mine = &accb[wid][lane][0];
#pragma unroll
        for (int f = 0; f < 4; ++f)
#pragma unroll
            for (int r = 0; r < 4; ++r) mine[f * 4 + r] = o[f][0][r];
    }
    __syncthreads();

    const int e = tid >> 6;                 // 0..15 (uniform per merge wave)
    const int lane_s = tid & 63;
    const int lo_s = lane_s & 15, hi_s = lane_s >> 4;
    const int fm = e >> 2, r = e & 3;
    const int ql = 16 * fm + 4 * hi_s + r;  // q within block
    float lm = 0.f;
    {
        float sum = 0.f;
#pragma unroll
        for (int s = 0; s < 16; ++s) {
            sum += accb[s][lane_s][e];
            lm  += lbuf[s][fm][4 * hi_s + r];
        }
        av[(q0 + ql) * CCH + hc + lo_s] = f2b(sum / lm);
    }
    __syncthreads();
    {
        float* mine = &accb[wid][lane][0];
#pragma unroll
        for (int f = 0; f < 4; ++f)
#pragma unroll
            for (int r2 = 0; r2 < 4; ++r2) mine[f * 4 + r2] = o[f][1][r2];
    }
    __syncthreads();
    {
        float sum = 0.f;
#pragma unroll
        for (int s = 0; s < 16; ++s) sum += accb[s][lane_s][e];
        av[(q0 + ql) * CCH + hc + 16 + lo_s] = f2b(sum / lm);
    }
}

// ---------------- c1b: h1 = h1a + W'@av + b', bf16 out, BN sums via atomics ----------------
__global__ __launch_bounds__(256) void c1b_kernel(
    const short* __restrict__ avb, const short* __restrict__ wpb,
    const float* __restrict__ bprime, const short* __restrict__ h1ab,
    short* __restrict__ h1, float* __restrict__ part)
{
    const int tid = threadIdx.x;
    const int w = tid >> 6, lane = tid & 63;
    const int lo = lane & 15, hi = lane >> 4;
    const int n0 = blockIdx.x * 32 + (w & 1) * 16;
    const int o0 = blockIdx.y * 64 + (w >> 1) * 32;
    const f32x4 z = {0.f, 0.f, 0.f, 0.f};
    f32x4 acc[2] = {z, z};
    gemm_accs<2, 0>(n0, o0, lo, hi, avb, CCH, wpb, CCH, 128, nullptr, nullptr, acc);

    const int oa = o0 + lo, ob = o0 + 16 + lo;
    float s0 = 0.f, q0 = 0.f, s1 = 0.f, q1 = 0.f;
#pragma unroll
    for (int r = 0; r < 4; ++r) {
        int n = n0 + 4 * hi + r;
        float v0 = acc[0][r] + bprime[oa] + b2f(h1ab[n * 256 + oa]);
        float v1 = acc[1][r] + bprime[ob] + b2f(h1ab[n * 256 + ob]);
        h1[n * 256 + oa] = f2b(v0);
        h1[n * 256 + ob] = f2b(v1);
        s0 += v0; q0 += v0 * v0; s1 += v1; q1 += v1 * v1;
    }
    s0 += __shfl_xor(s0, 16); s0 += __shfl_xor(s0, 32);
    q0 += __shfl_xor(q0, 16); q0 += __shfl_xor(q0, 32);
    s1 += __shfl_xor(s1, 16); s1 += __shfl_xor(s1, 32);
    q1 += __shfl_xor(q1, 16); q1 += __shfl_xor(q1, 32);
    if (hi == 0) {
        atomicAdd(&part[oa], s0);  atomicAdd(&part[256 + oa], q0);
        atomicAdd(&part[ob], s1);  atomicAdd(&part[256 + ob], q1);
    }
}

// ---------------- c2f: 256 blocks x 16 rows, BN+ReLU on load, fused final ----------------
__global__ __launch_bounds__(256) void c2f_kernel(
    const short* __restrict__ h1, const short* __restrict__ wbc2,
    const float* __restrict__ bc2f, const short* __restrict__ eb,
    const float* __restrict__ part, const float* __restrict__ gf,
    const float* __restrict__ bef, const float* __restrict__ wtf,
    const float* __restrict__ btf, void* __restrict__ out,
    const int* __restrict__ flagp)
{
    __shared__ float scL[256], shL[256], wts[384];
    __shared__ float red[4][16][3];
    const int tid = threadIdx.x;
    {
        float mean = part[tid] * (1.f / NPTS);
        float var  = part[256 + tid] * (1.f / NPTS) - mean * mean;
        float iv   = rsqrtf(var + 1e-5f);
        float sc   = gf[tid] * iv;
        scL[tid] = sc;
        shL[tid] = bef[tid] - mean * sc;
    }
    for (int i = tid; i < 384; i += 256) wts[i] = wtf[i];
    __syncthreads();

    const int w = tid >> 6, lane = tid & 63;
    const int lo = lane & 15, hi = lane >> 4;
    const int n0 = blockIdx.x * 16;
    const int o0 = w * 32;
    const f32x4 z = {0.f, 0.f, 0.f, 0.f};
    f32x4 acc[2] = {z, z};
    gemm_accs<2, 1>(n0, o0, lo, hi, h1, 256, wbc2, 256, 256, scL, shL, acc);

    float pr[4][3] = {};
#pragma unroll
    for (int f = 0; f < 2; ++f) {
        int col = o0 + 16 * f + lo;
        float w0 = wts[col], w1 = wts[128 + col], w2 = wts[256 + col];
        float bb = bc2f[col];
#pragma unroll
        for (int r = 0; r < 4; ++r) {
            int n = n0 + 4 * hi + r;
            float v = acc[f][r] + bb + b2f(eb[n * CCH + col]);
            pr[r][0] += v * w0; pr[r][1] += v * w1; pr[r][2] += v * w2;
        }
    }
#pragma unroll
    for (int r = 0; r < 4; ++r)
#pragma unroll
        for (int d = 0; d < 3; ++d) {
            float x = pr[r][d];
            x += __shfl_xor(x, 1); x += __shfl_xor(x, 2);
            x += __shfl_xor(x, 4); x += __shfl_xor(x, 8);
            pr[r][d] = x;
        }
    if (lo == 0) {
#pragma unroll
        for (int r = 0; r < 4; ++r)
#pragma unroll
            for (int d = 0; d < 3; ++d)
                red[w][4 * hi + r][d] = pr[r][d];
    }
    __syncthreads();
    if (tid < 48) {
        int nl = tid / 3, d = tid - nl * 3;
        float v = red[0][nl][d] + red[1][nl][d] + red[2][nl][d] + red[3][nl][d] + btf[d];
        int gn = blockIdx.x * 16 + nl;
        if (*flagp) ((float*)out)[gn * 3 + d] = v;
        else        ((bf16*)out)[gn * 3 + d] = __float2bfloat16(v);
    }
}

extern "C" void kernel_launch(void* const* d_in, const int* in_sizes, int n_in,
                              void* d_out, int out_size, void* d_ws, size_t ws_size,
                              hipStream_t stream) {
    const int CN = CCH * NPTS;  // 524288
    float* ws = (float*)d_ws;
    size_t fo = 0;
    auto FA = [&](size_t n) { float* p = ws + fo; fo += n; return p; };
    short* eb     = (short*)FA(CN / 2);    // bf16 [4096][128]
    short* qfb    = (short*)FA(CN / 2);    // bf16 Q fragment-linear [4][256][512]
    short* kfb    = (short*)FA(CN / 2);    // bf16 K fragment-linear
    short* vfb    = (short*)FA(CN / 2);    // bf16 V fragment-linear (sigma slots)
    short* avb    = (short*)FA(CN / 2);    // bf16 [4096][128]
    short* h1ab   = (short*)FA(CN);        // bf16 [4096][256]
    short* h1     = (short*)FA(CN);        // bf16 [4096][256]
    short* wpb    = (short*)FA(16384);     // bf16 [256][128]
    short* wmhT   = (short*)FA(8192);      // bf16 [128][128]
    float* bprime = FA(256);
    float* part   = FA(512);
    int*   flagp  = (int*)FA(16);
    float* wfa    = ws + fo;

    WPtrs P;
    int acc = 0;
    int st[17];
    for (int i = 1; i < 17; ++i) {
        P.src[i - 1] = d_in[i];
        P.start[i - 1] = acc;
        st[i] = acc;
        acc += (in_sizes[i] + 3) & ~3;
    }
    P.start[16] = acc;
    short* wba = (short*)(wfa + acc);

    const short* wbq  = wba + st[1];
    const short* wbk  = wba + st[3];
    const short* wbv  = wba + st[5];
    const short* wbc1 = wba + st[9];
    const short* wbc2 = wba + st[13];
    const float* bqf  = wfa + st[2];
    const float* bkf  = wfa + st[4];
    const float* bvf  = wfa + st[6];
    const float* bmhf = wfa + st[8];
    const float* wc1f = wfa + st[9];
    const float* bc1f = wfa + st[10];
    const float* gf   = wfa + st[11];
    const float* bef  = wfa + st[12];
    const float* bc2f = wfa + st[14];
    const float* wtf  = wfa + st[15];
    const float* btf  = wfa + st[16];

    const int NW = (acc + 255) / 256;
    prep_kernel<<<128 + NW, 256, 0, stream>>>(d_in[0], P, eb, wfa, wba, wmhT,
                                              part, flagp, acc);

    qkv_kernel<<<777, 256, 0, stream>>>(eb, wbq, wbk, wbv, wbc1, wmhT,
                                        bqf, bkf, bvf, bc1f, bmhf, wc1f,
                                        qfb, kfb, vfb, h1ab, wpb, bprime);

    attn_kernel<<<4 * 64, 1024, 0, stream>>>(qfb, kfb, vfb, avb);

    c1b_kernel<<<dim3(128, 4), 256, 0, stream>>>(avb, wpb, bprime, h1ab, h1, part);

    c2f_kernel<<<256, 256, 0, stream>>>(h1, wbc2, bc2f, eb, part, gf, bef,
                                        wtf, btf, d_out, flagp);
}

// Round 15
// 57.922 us; speedup vs baseline: 3.2003x; 1.1928x over previous
//
#include <hip/hip_runtime.h>
#include <hip/hip_bf16.h>

typedef __hip_bfloat16 bf16;
typedef __attribute__((ext_vector_type(8))) short short8;
typedef __attribute__((ext_vector_type(4))) float f32x4;

#define NPTS 4096
#define CCH  128

static __device__ __forceinline__ short f2b(float x) {
    bf16 h = __float2bfloat16(x);
    return __builtin_bit_cast(short, h);
}
static __device__ __forceinline__ float b2f(short x) {
    return __bfloat162float(__builtin_bit_cast(bf16, x));
}

struct WPtrs { const void* src[16]; int start[17]; };

// ---------------- prep: detect + eigen transpose(bf16) + weight convert ----------------
__global__ __launch_bounds__(256) void prep_kernel(
    const void* __restrict__ eigen, WPtrs P,
    short* __restrict__ eb,
    float* __restrict__ wfa, short* __restrict__ wba, short* __restrict__ wmhT,
    float* __restrict__ part, int* __restrict__ flagp, int total)
{
    const int tid = threadIdx.x, bid = blockIdx.x;
    __shared__ int sflag;
    {
        int cnt = 0;
        if (tid < 64) {
            const unsigned short* u = (const unsigned short*)eigen;
#pragma unroll
            for (int i = 0; i < 16; ++i) {
                int e = (u[tid * 16 + i] >> 7) & 0xFF;
                cnt += (e >= 0x8F);
            }
#pragma unroll
            for (int off = 32; off > 0; off >>= 1) cnt += __shfl_down(cnt, off);
            if (tid == 0) sflag = (cnt >= 16);
        }
        __syncthreads();
    }
    const int f = sflag;

    if (bid < 128) {
        __shared__ float tile[64][65];
        const int tx = tid & 63, ty = tid >> 6;
        const int n0 = (bid & 63) * 64, c0 = (bid >> 6) * 64;
#pragma unroll
        for (int it = 0; it < 16; ++it) {
            int cl = 4 * it + ty;
            float v = f ? ((const float*)eigen)[(c0 + cl) * NPTS + n0 + tx]
                        : b2f(((const short*)eigen)[(c0 + cl) * NPTS + n0 + tx]);
            tile[tx][cl] = v;
        }
        __syncthreads();
#pragma unroll
        for (int ot = 0; ot < 16; ++ot) {
            int nl = 4 * ot + ty;
            eb[(n0 + nl) * CCH + c0 + tx] = f2b(tile[nl][tx]);
        }
    } else {
        if (bid == 128) {
            if (tid == 0) *flagp = f;
            part[tid] = 0.f; part[256 + tid] = 0.f;
        }
        int i = (bid - 128) * 256 + tid;
        if (i < total) {
            int s = 0;
#pragma unroll 1
            for (int k2 = 0; k2 < 16; ++k2) if (i >= P.start[k2 + 1]) s = k2 + 1;
            int off = i - P.start[s];
            float v = f ? ((const float*)P.src[s])[off]
                        : b2f(((const short*)P.src[s])[off]);
            // fold 1/sqrt(hd) * log2(e) into wq,bq -> softmax uses exp2 directly
            if (s < 2) v *= 0.25503506f;
            wfa[i] = v;
            short vb = f2b(v);
            wba[i] = vb;
            if (s == 6) wmhT[(off & 127) * 128 + (off >> 7)] = vb;  // wmh^T
        }
    }
}

// ---------------- MFMA acc core: acc[f] += A[n][:]·W[o0+16f+lo][:] ----------------
template<int OFRAG, int BNA>
static __device__ __forceinline__ void gemm_accs(
    int n0, int o0, int lo, int hi,
    const short* __restrict__ A, int alda,
    const short* __restrict__ W, int wlda, int K,
    const float* scL, const float* shL, f32x4* acc)
{
    const short* Ar = A + (n0 + lo) * alda + 8 * hi;
#pragma unroll 4
    for (int kk = 0; kk < K; kk += 32) {
        short8 aF = *(const short8*)(Ar + kk);
        if (BNA) {
#pragma unroll
            for (int j = 0; j < 8; ++j) {
                int c = kk + 8 * hi + j;
                aF[j] = f2b(fmaxf(scL[c] * b2f(aF[j]) + shL[c], 0.f));
            }
        }
#pragma unroll
        for (int f = 0; f < OFRAG; ++f) {
            short8 bF = *(const short8*)(W + (o0 + 16 * f + lo) * wlda + 8 * hi + kk);
            acc[f] = __builtin_amdgcn_mfma_f32_16x16x32_bf16(aF, bF, acc[f], 0, 0, 0);
        }
    }
}

// ---------------- swapped GEMM (V): fragment-linear output ----------------
// Vf layout: addr(head, m, c32) = ((head*128 + (m>>5))*2 + (c32>>4))*512
//            + (s>>3)*128 + (c32&15)*8 + (s&7),  s = 8*((m>>2)&3)+(m&3)+4*((m>>4)&1)
static __device__ __forceinline__ void gemm_tn_body(
    int bx, int by, int tid,
    const short* __restrict__ W, const short* __restrict__ A,
    const float* __restrict__ bias, short* __restrict__ out)
{
    const int w = tid >> 6, lane = tid & 63;
    const int lo = lane & 15, hi = lane >> 4;
    const int o0 = by * 16;
    const int n0 = bx * 128 + w * 32;
    const f32x4 z = {0.f, 0.f, 0.f, 0.f};
    f32x4 acc0 = z, acc1 = z;
    const short* Wr = W + (o0 + lo) * CCH + 8 * hi;
    const short* A0 = A + (n0 + lo) * CCH + 8 * hi;
    const short* A1 = A + (n0 + 16 + lo) * CCH + 8 * hi;
#pragma unroll
    for (int kk = 0; kk < 128; kk += 32) {
        short8 aW = *(const short8*)(Wr + kk);
        short8 b0 = *(const short8*)(A0 + kk);
        short8 b1 = *(const short8*)(A1 + kk);
        acc0 = __builtin_amdgcn_mfma_f32_16x16x32_bf16(aW, b0, acc0, 0, 0, 0);
        acc1 = __builtin_amdgcn_mfma_f32_16x16x32_bf16(aW, b1, acc1, 0, 0, 0);
    }
    const int s1 = 8 * (lo >> 2) + (lo & 3);
    const int s2 = s1 + 4;
    const int m32 = n0 >> 5;
#pragma unroll
    for (int r = 0; r < 4; ++r) {
        int o = o0 + 4 * hi + r;
        float bb = bias[o];
        int hd = o >> 5, c32 = o & 31, dt = c32 >> 4, lov = c32 & 15;
        int base = ((hd * 128 + m32) * 2 + dt) * 512 + lov * 8;
        out[base + (s1 >> 3) * 128 + (s1 & 7)] = f2b(acc0[r] + bb);
        out[base + (s2 >> 3) * 128 + (s2 & 7)] = f2b(acc1[r] + bb);
    }
}

// ---------------- pre-attention fused launch: QK | h1a | V | W' | b' ----------------
__global__ __launch_bounds__(256) void qkv_kernel(
    const short* __restrict__ eb,
    const short* __restrict__ wbq, const short* __restrict__ wbk,
    const short* __restrict__ wbv, const short* __restrict__ wbc1,
    const short* __restrict__ wmhT,
    const float* __restrict__ bqf, const float* __restrict__ bkf,
    const float* __restrict__ bvf, const float* __restrict__ bc1f,
    const float* __restrict__ bmhf, const float* __restrict__ wc1f,
    short* __restrict__ qfb, short* __restrict__ kfb, short* __restrict__ vfb,
    short* __restrict__ h1ab, short* __restrict__ wpb, float* __restrict__ bprime)
{
    const int bid = blockIdx.x, tid = threadIdx.x;
    const int w = tid >> 6, lane = tid & 63;
    const int lo = lane & 15, hi = lane >> 4;
    const f32x4 z = {0.f, 0.f, 0.f, 0.f};

    if (bid < 256) {            // Q (bid<128) or K -> fragment-linear buffers
        const int isK = bid >> 7, bx = bid & 127;
        const int n0 = bx * 32 + (w & 1) * 16, o0 = (w >> 1) * 64;
        f32x4 acc[4] = {z, z, z, z};
        gemm_accs<4, 0>(n0, o0, lo, hi, eb, CCH, isK ? wbk : wbq, CCH, 128,
                        nullptr, nullptr, acc);
        const float* bp = isK ? bkf : bqf;
        short* dst = isK ? kfb : qfb;
        const int tile = n0 >> 4;
#pragma unroll
        for (int f = 0; f < 4; ++f) {
            int col = o0 + 16 * f + lo;
            int hd = col >> 5, c32 = col & 31;
            int base = hd * 131072 + tile * 512 + (c32 >> 3) * 128 + (c32 & 7);
#pragma unroll
            for (int r = 0; r < 4; ++r)
                dst[base + (4 * hi + r) * 8] = f2b(acc[f][r] + bp[col]);
        }
    } else if (bid < 512) {     // h1a = wc1a @ eigen, bf16 [4096][256]
        const int b3 = bid - 256, bx = b3 & 127, by = b3 >> 7;
        const int n0 = bx * 32 + (w & 1) * 16, o0 = by * 128 + (w >> 1) * 64;
        f32x4 acc[4] = {z, z, z, z};
        gemm_accs<4, 0>(n0, o0, lo, hi, eb, CCH, wbc1, 256, 128, nullptr, nullptr, acc);
#pragma unroll
        for (int f = 0; f < 4; ++f) {
            int col = o0 + 16 * f + lo;
#pragma unroll
            for (int r = 0; r < 4; ++r)
                h1ab[(n0 + 4 * hi + r) * 256 + col] = f2b(acc[f][r]);
        }
    } else if (bid < 768) {     // V -> fragment-linear vfb
        int b2 = bid - 512;
        gemm_tn_body(b2 & 31, b2 >> 5, tid, wbv, eb, bvf, vfb);
    } else if (bid < 776) {     // W' = wc1b @ wmh, bf16 [256][128]
        const int bx = bid - 768;
        const int n0 = bx * 32 + (w & 1) * 16, o0 = (w >> 1) * 64;
        f32x4 acc[4] = {z, z, z, z};
        gemm_accs<4, 0>(n0, o0, lo, hi, wbc1 + 128, 256, wmhT, 128, 128,
                        nullptr, nullptr, acc);
#pragma unroll
        for (int f = 0; f < 4; ++f) {
            int col = o0 + 16 * f + lo;
#pragma unroll
            for (int r = 0; r < 4; ++r)
                wpb[(n0 + 4 * hi + r) * 128 + col] = f2b(acc[f][r]);
        }
    } else {                    // b' = bc1 + wc1b @ bmh
        float a = bc1f[tid];
        const float* row = wc1f + tid * 256 + 128;
#pragma unroll 8
        for (int k = 0; k < 128; ++k) a = fmaf(row[k], bmhf[k], a);
        bprime[tid] = a;
    }
}

// ---------------- MFMA flash attention: fragment-linear operands, 64q/wave ----------------
// grid = H*64 blocks x 1024 thr (16 waves = 16-way KV split, each wave does 64 q).
// All Q/K/V fragment loads are single contiguous 1KB wave transactions.
// (round-12 loop restored: no register double-buffer — compiler scheduling wins)
__global__ __launch_bounds__(1024, 4) void attn_kernel(
    const short* __restrict__ qF, const short* __restrict__ kF,
    const short* __restrict__ vF, short* __restrict__ av) {
    const int tid = threadIdx.x;
    const int wid = tid >> 6, lane = tid & 63;
    const int lo = lane & 15, hi = lane >> 4;
    const int h = blockIdx.x >> 6;
    const int qblk = blockIdx.x & 63;
    const int q0 = qblk * 64;
    const int hc = h * 32;
    const int lofs = hi * 128 + lo * 8;

    __shared__ __align__(16) float accb[16][64][17];  // 69.6 KB, pad-17 bank-free
    __shared__ float lbuf[16][4][16];                  // 4 KB row-sum partials

    const short* qh = qF + h * 131072;
    const short* kh = kF + h * 131072;
    const short* vh = vF + h * 131072;

    short8 qf[4];
#pragma unroll
    for (int f = 0; f < 4; ++f)
        qf[f] = *(const short8*)(qh + ((q0 >> 4) + f) * 512 + lofs);

    const f32x4 z = {0.f, 0.f, 0.f, 0.f};
    f32x4 o[4][2] = {{z, z}, {z, z}, {z, z}, {z, z}};  // o[f][dt]
    float l[4] = {0.f, 0.f, 0.f, 0.f};

    for (int t = 0; t < 4; ++t) {
        const int m0 = wid * 256 + t * 64;
        short8 kf[4], vf[4];
#pragma unroll
        for (int mt = 0; mt < 4; ++mt)
            kf[mt] = *(const short8*)(kh + ((m0 >> 4) + mt) * 512 + lofs);
#pragma unroll
        for (int kt = 0; kt < 2; ++kt)
#pragma unroll
            for (int dt = 0; dt < 2; ++dt)
                vf[kt * 2 + dt] = *(const short8*)(vh + (((m0 >> 5) + kt) * 2 + dt) * 512 + lofs);

#pragma unroll
        for (int f = 0; f < 4; ++f) {
            f32x4 s[4];
#pragma unroll
            for (int mt = 0; mt < 4; ++mt)
                s[mt] = __builtin_amdgcn_mfma_f32_16x16x32_bf16(kf[mt], qf[f], z, 0, 0, 0);

            float p[4][4];
            float sm = 0.f;
#pragma unroll
            for (int mt = 0; mt < 4; ++mt)
#pragma unroll
                for (int r = 0; r < 4; ++r) {
                    float pv = __builtin_amdgcn_exp2f(s[mt][r]);
                    p[mt][r] = pv;
                    sm += pv;
                }
            sm += __shfl_xor(sm, 16);
            sm += __shfl_xor(sm, 32);
            l[f] += sm;

            short8 pa1, pa2;
#pragma unroll
            for (int j = 0; j < 8; ++j) {
                pa1[j] = f2b(p[j >> 2][j & 3]);
                pa2[j] = f2b(p[2 + (j >> 2)][j & 3]);
            }
            o[f][0] = __builtin_amdgcn_mfma_f32_16x16x32_bf16(pa1, vf[0], o[f][0], 0, 0, 0);
            o[f][1] = __builtin_amdgcn_mfma_f32_16x16x32_bf16(pa1, vf[1], o[f][1], 0, 0, 0);
            o[f][0] = __builtin_amdgcn_mfma_f32_16x16x32_bf16(pa2, vf[2], o[f][0], 0, 0, 0);
            o[f][1] = __builtin_amdgcn_mfma_f32_16x16x32_bf16(pa2, vf[3], o[f][1], 0, 0, 0);
        }
    }

    // ---- merge 16 KV partials, two d-half phases, all-wave parallel ----
    if (hi == 0) {
#pragma unroll
        for (int f = 0; f < 4; ++f) lbuf[wid][f][lo] = l[f];
    }
    {
        float* mine = &accb[wid][lane][0];
#pragma unroll
        for (int f = 0; f < 4; ++f)
#pragma unroll
            for (int r = 0; r < 4; ++r) mine[f * 4 + r] = o[f][0][r];
    }
    __syncthreads();

    const int e = tid >> 6;                 // 0..15 (uniform per merge wave)
    const int lane_s = tid & 63;
    const int lo_s = lane_s & 15, hi_s = lane_s >> 4;
    const int fm = e >> 2, r = e & 3;
    const int ql = 16 * fm + 4 * hi_s + r;  // q within block
    float lm = 0.f;
    {
        float sum = 0.f;
#pragma unroll
        for (int s = 0; s < 16; ++s) {
            sum += accb[s][lane_s][e];
            lm  += lbuf[s][fm][4 * hi_s + r];
        }
        av[(q0 + ql) * CCH + hc + lo_s] = f2b(sum / lm);
    }
    __syncthreads();
    {
        float* mine = &accb[wid][lane][0];
#pragma unroll
        for (int f = 0; f < 4; ++f)
#pragma unroll
            for (int r2 = 0; r2 < 4; ++r2) mine[f * 4 + r2] = o[f][1][r2];
    }
    __syncthreads();
    {
        float sum = 0.f;
#pragma unroll
        for (int s = 0; s < 16; ++s) sum += accb[s][lane_s][e];
        av[(q0 + ql) * CCH + hc + 16 + lo_s] = f2b(sum / lm);
    }
}

// ---------------- c1b: h1 = h1a + W'@av + b', bf16 out, BN sums via atomics ----------------
__global__ __launch_bounds__(256) void c1b_kernel(
    const short* __restrict__ avb, const short* __restrict__ wpb,
    const float* __restrict__ bprime, const short* __restrict__ h1ab,
    short* __restrict__ h1, float* __restrict__ part)
{
    const int tid = threadIdx.x;
    const int w = tid >> 6, lane = tid & 63;
    const int lo = lane & 15, hi = lane >> 4;
    const int n0 = blockIdx.x * 32 + (w & 1) * 16;
    const int o0 = blockIdx.y * 64 + (w >> 1) * 32;
    const f32x4 z = {0.f, 0.f, 0.f, 0.f};
    f32x4 acc[2] = {z, z};
    gemm_accs<2, 0>(n0, o0, lo, hi, avb, CCH, wpb, CCH, 128, nullptr, nullptr, acc);

    const int oa = o0 + lo, ob = o0 + 16 + lo;
    float s0 = 0.f, q0 = 0.f, s1 = 0.f, q1 = 0.f;
#pragma unroll
    for (int r = 0; r < 4; ++r) {
        int n = n0 + 4 * hi + r;
        float v0 = acc[0][r] + bprime[oa] + b2f(h1ab[n * 256 + oa]);
        float v1 = acc[1][r] + bprime[ob] + b2f(h1ab[n * 256 + ob]);
        h1[n * 256 + oa] = f2b(v0);
        h1[n * 256 + ob] = f2b(v1);
        s0 += v0; q0 += v0 * v0; s1 += v1; q1 += v1 * v1;
    }
    s0 += __shfl_xor(s0, 16); s0 += __shfl_xor(s0, 32);
    q0 += __shfl_xor(q0, 16); q0 += __shfl_xor(q0, 32);
    s1 += __shfl_xor(s1, 16); s1 += __shfl_xor(s1, 32);
    q1 += __shfl_xor(q1, 16); q1 += __shfl_xor(q1, 32);
    if (hi == 0) {
        atomicAdd(&part[oa], s0);  atomicAdd(&part[256 + oa], q0);
        atomicAdd(&part[ob], s1);  atomicAdd(&part[256 + ob], q1);
    }
}

// ---------------- c2f: 256 blocks x 16 rows, BN+ReLU on load, fused final ----------------
__global__ __launch_bounds__(256) void c2f_kernel(
    const short* __restrict__ h1, const short* __restrict__ wbc2,
    const float* __restrict__ bc2f, const short* __restrict__ eb,
    const float* __restrict__ part, const float* __restrict__ gf,
    const float* __restrict__ bef, const float* __restrict__ wtf,
    const float* __restrict__ btf, void* __restrict__ out,
    const int* __restrict__ flagp)
{
    __shared__ float scL[256], shL[256], wts[384];
    __shared__ float red[4][16][3];
    const int tid = threadIdx.x;
    {
        float mean = part[tid] * (1.f / NPTS);
        float var  = part[256 + tid] * (1.f / NPTS) - mean * mean;
        float iv   = rsqrtf(var + 1e-5f);
        float sc   = gf[tid] * iv;
        scL[tid] = sc;
        shL[tid] = bef[tid] - mean * sc;
    }
    for (int i = tid; i < 384; i += 256) wts[i] = wtf[i];
    __syncthreads();

    const int w = tid >> 6, lane = tid & 63;
    const int lo = lane & 15, hi = lane >> 4;
    const int n0 = blockIdx.x * 16;
    const int o0 = w * 32;
    const f32x4 z = {0.f, 0.f, 0.f, 0.f};
    f32x4 acc[2] = {z, z};
    gemm_accs<2, 1>(n0, o0, lo, hi, h1, 256, wbc2, 256, 256, scL, shL, acc);

    float pr[4][3] = {};
#pragma unroll
    for (int f = 0; f < 2; ++f) {
        int col = o0 + 16 * f + lo;
        float w0 = wts[col], w1 = wts[128 + col], w2 = wts[256 + col];
        float bb = bc2f[col];
#pragma unroll
        for (int r = 0; r < 4; ++r) {
            int n = n0 + 4 * hi + r;
            float v = acc[f][r] + bb + b2f(eb[n * CCH + col]);
            pr[r][0] += v * w0; pr[r][1] += v * w1; pr[r][2] += v * w2;
        }
    }
#pragma unroll
    for (int r = 0; r < 4; ++r)
#pragma unroll
        for (int d = 0; d < 3; ++d) {
            float x = pr[r][d];
            x += __shfl_xor(x, 1); x += __shfl_xor(x, 2);
            x += __shfl_xor(x, 4); x += __shfl_xor(x, 8);
            pr[r][d] = x;
        }
    if (lo == 0) {
#pragma unroll
        for (int r = 0; r < 4; ++r)
#pragma unroll
            for (int d = 0; d < 3; ++d)
                red[w][4 * hi + r][d] = pr[r][d];
    }
    __syncthreads();
    if (tid < 48) {
        int nl = tid / 3, d = tid - nl * 3;
        float v = red[0][nl][d] + red[1][nl][d] + red[2][nl][d] + red[3][nl][d] + btf[d];
        int gn = blockIdx.x * 16 + nl;
        if (*flagp) ((float*)out)[gn * 3 + d] = v;
        else        ((bf16*)out)[gn * 3 + d] = __float2bfloat16(v);
    }
}

extern "C" void kernel_launch(void* const* d_in, const int* in_sizes, int n_in,
                              void* d_out, int out_size, void* d_ws, size_t ws_size,
                              hipStream_t stream) {
    const int CN = CCH * NPTS;  // 524288
    float* ws = (float*)d_ws;
    size_t fo = 0;
    auto FA = [&](size_t n) { float* p = ws + fo; fo += n; return p; };
    short* eb     = (short*)FA(CN / 2);    // bf16 [4096][128]
    short* qfb    = (short*)FA(CN / 2);    // bf16 Q fragment-linear [4][256][512]
    short* kfb    = (short*)FA(CN / 2);    // bf16 K fragment-linear
    short* vfb    = (short*)FA(CN / 2);    // bf16 V fragment-linear (sigma slots)
    short* avb    = (short*)FA(CN / 2);    // bf16 [4096][128]
    short* h1ab   = (short*)FA(CN);        // bf16 [4096][256]
    short* h1     = (short*)FA(CN);        // bf16 [4096][256]
    short* wpb    = (short*)FA(16384);     // bf16 [256][128]
    short* wmhT   = (short*)FA(8192);      // bf16 [128][128]
    float* bprime = FA(256);
    float* part   = FA(512);
    int*   flagp  = (int*)FA(16);
    float* wfa    = ws + fo;

    WPtrs P;
    int acc = 0;
    int st[17];
    for (int i = 1; i < 17; ++i) {
        P.src[i - 1] = d_in[i];
        P.start[i - 1] = acc;
        st[i] = acc;
        acc += (in_sizes[i] + 3) & ~3;
    }
    P.start[16] = acc;
    short* wba = (short*)(wfa + acc);

    const short* wbq  = wba + st[1];
    const short* wbk  = wba + st[3];
    const short* wbv  = wba + st[5];
    const short* wbc1 = wba + st[9];
    const short* wbc2 = wba + st[13];
    const float* bqf  = wfa + st[2];
    const float* bkf  = wfa + st[4];
    const float* bvf  = wfa + st[6];
    const float* bmhf = wfa + st[8];
    const float* wc1f = wfa + st[9];
    const float* bc1f = wfa + st[10];
    const float* gf   = wfa + st[11];
    const float* bef  = wfa + st[12];
    const float* bc2f = wfa + st[14];
    const float* wtf  = wfa + st[15];
    const float* btf  = wfa + st[16];

    const int NW = (acc + 255) / 256;
    prep_kernel<<<128 + NW, 256, 0, stream>>>(d_in[0], P, eb, wfa, wba, wmhT,
                                              part, flagp, acc);

    qkv_kernel<<<777, 256, 0, stream>>>(eb, wbq, wbk, wbv, wbc1, wmhT,
                                        bqf, bkf, bvf, bc1f, bmhf, wc1f,
                                        qfb, kfb, vfb, h1ab, wpb, bprime);

    attn_kernel<<<4 * 64, 1024, 0, stream>>>(qfb, kfb, vfb, avb);

    c1b_kernel<<<dim3(128, 4), 256, 0, stream>>>(avb, wpb, bprime, h1ab, h1, part);

    c2f_kernel<<<256, 256, 0, stream>>>(h1, wbc2, bc2f, eb, part, gf, bef,
                                        wtf, btf, d_out, flagp);
}